// Round 10
// baseline (213.122 us; speedup 1.0000x reference)
//
#include <hip/hip_runtime.h>
#include <math.h>

#define D1 768
#define D2R 385
#define NF 295680   // 768*385
#define KNUM 4
#define NB 8
#define NC 256
#define INV768 0.0013020833333333333f

// ---------------- ws layout (bytes) --------------------------------------
// specB  bf16 [4][448 c-rows][1536 k]   @ 0           B^T stage A
// Atw    bf16 [2][768 m][1536 k]        @ 6,291,456   A stage A
// Ya     bf16 [4][768 m][800 k]         @ 11,010,048  A stage B
// T      bf16 [768 n][800 k]            @ 15,925,248  B^T stage B
// wBF    bf16 [8][144 step][256 oc][16] @ 0           overlays specB+Atw
//   (specB/Atw dead after fftA; fftBW reads Ya/T and writes wBF@0 -> no
//    overlap race. Old wBF@9.4MB overlapped Ya/T and would race the fused
//    kernel. Max ws use now 17,154,048 B.)
#define ATW_U32 1572864u
#define YA_U32 2752512u
#define T_U32 3981312u
#define SPECB_K_U32 344064u  // 448*768 uints per k

typedef __attribute__((ext_vector_type(8))) short short8;
typedef __attribute__((ext_vector_type(16))) float f32x16;
union U4S8 { unsigned int u[4]; uint4 u4; short8 s8; };

static __device__ __forceinline__ unsigned int f2bf(float f) {
  unsigned int u = __float_as_uint(f);
  return (u + 0x7fffu + ((u >> 16) & 1u)) >> 16;  // RNE, no NaN inputs
}

static __device__ __forceinline__ void sincos_rev768(int idx, float* s,
                                                     float* c) {
  float rev = (float)idx * INV768;
  *s = __builtin_amdgcn_sinf(rev);
  *c = __builtin_amdgcn_cosf(rev);
}

// raw barrier: LDS-drain only; register-dest vmem loads stay in flight.
static __device__ __forceinline__ void barrier_lgkm() {
  asm volatile("s_waitcnt lgkmcnt(0)" ::: "memory");
  __builtin_amdgcn_sched_barrier(0);
  __builtin_amdgcn_s_barrier();
  __builtin_amdgcn_sched_barrier(0);
}

// ---------------- prep v2: 4 elems/thread, vectorized IO -----------------
__global__ __launch_bounds__(256) void prep_kernel(
    const float* __restrict__ dw, const int* __restrict__ fh,
    const int* __restrict__ fw, unsigned int* __restrict__ ws) {
  int q = blockIdx.x * 256 + threadIdx.x;  // grid 2841 -> 727296 quads
  if (q < 295680) {  // scatter: 4 consecutive r of one k
    int k = q / 73920;
    int ql = q - k * 73920;  // int4 index into fh/fw
    long f2i = (long)k * NF + (long)ql * 4;
    const float4 v0 = ((const float4*)dw)[f2i >> 1];
    const float4 v1 = ((const float4*)dw)[(f2i >> 1) + 1];
    const int4 h4 = ((const int4*)fh)[ql];
    const int4 c4 = ((const int4*)fw)[ql];
    size_t kb = (size_t)k * SPECB_K_U32;
    ws[kb + (size_t)c4.x * 768 + h4.x] = f2bf(v0.x) | (f2bf(v0.y) << 16);
    ws[kb + (size_t)c4.y * 768 + h4.y] = f2bf(v0.z) | (f2bf(v0.w) << 16);
    ws[kb + (size_t)c4.z * 768 + h4.z] = f2bf(v1.x) | (f2bf(v1.y) << 16);
    ws[kb + (size_t)c4.w * 768 + h4.w] = f2bf(v1.z) | (f2bf(v1.w) << 16);
    return;
  }
  int j = q - 295680;
  if (j < 294912) {  // Atw: 4 consecutive h of one (ri,m)
    int j0 = j * 4;
    int ri = j0 / 589824;
    int rem = j0 - ri * 589824;
    int m = rem / 768, h0 = rem - (rem / 768) * 768;
    uint4 o;
#pragma unroll
    for (int e = 0; e < 4; ++e) {
      int idx = ((h0 + e) * m) % 768;
      float s, c;
      sincos_rev768(idx, &s, &c);
      unsigned lo, hi;
      if (ri == 0) { lo = f2bf(c); hi = f2bf(-s); }
      else         { lo = f2bf(s); hi = f2bf(c); }
      ((unsigned*)&o)[e] = lo | (hi << 16);
    }
    *(uint4*)(ws + ATW_U32 + j0) = o;
  } else if (j < 371712) {  // T^T: 4 consecutive cc of one n
    int p0 = (j - 294912) * 4;
    int n = p0 / 400, cc0 = p0 - (p0 / 400) * 400;
    uint4 o;
#pragma unroll
    for (int e = 0; e < 4; ++e) {
      int cc = cc0 + e;
      unsigned v = 0;
      if (cc <= 384) {
        float wgt = (cc == 0 || cc == 384) ? 1.6954210069444445e-6f
                                           : 3.390842013888889e-6f;
        int idx = (cc * n) % 768;
        float s, c;
        sincos_rev768(idx, &s, &c);
        v = f2bf(wgt * c) | (f2bf(-wgt * s) << 16);
      }
      ((unsigned*)&o)[e] = v;
    }
    *(uint4*)(ws + T_U32 + (size_t)n * 400 + cc0) = o;
  } else if (j < 420096) {  // specB zero rows 385..447 (uint4)
    int p0 = (j - 371712) * 4;
    int k = p0 / 48384;
    int r = p0 - k * 48384;
    int row = 385 + r / 768;
    int col = r - (r / 768) * 768;
    *(uint4*)(ws + (size_t)k * SPECB_K_U32 + (size_t)row * 768 + col) =
        make_uint4(0u, 0u, 0u, 0u);
  } else if (j < 431616) {  // Ya zero cols 770..799
    int p0 = (j - 420096) * 4;
#pragma unroll
    for (int e = 0; e < 4; ++e) {
      int p = p0 + e;
      int k = p / 11520;
      int r = p - k * 11520;
      int m = r / 15, jj = r - (r / 15) * 15;
      ws[YA_U32 + (size_t)k * 307200 + (size_t)m * 400 + 385 + jj] = 0u;
    }
  }
}

// ---------------- fftA v5: 64x64 tile + E/O pipeline, grid (12,7,8) ------
__global__ __launch_bounds__(256) void fftA_kernel(
    const unsigned short* __restrict__ Atw,
    const unsigned short* __restrict__ specB,
    unsigned short* __restrict__ Ya) {
  __shared__ __align__(16) unsigned short Al[2][64 * 40], Bl[2][64 * 40];
  int t = threadIdx.x;
  int mt = blockIdx.x, nt = blockIdx.y, z = blockIdx.z;
  int ri = z & 1, k = z >> 1;
  const unsigned short* Ag =
      Atw + (size_t)ri * 1179648 + (size_t)(mt * 64) * 1536;
  const unsigned short* Bg =
      specB + (size_t)k * 688128 + (size_t)(nt * 64) * 1536;
  int rowS = t >> 2, q = t & 3;
  int lane = t & 63, w = t >> 6;
  int mq = w & 1, nq = w >> 1;
  int lm = lane & 31, half = lane >> 5;
  int wr = rowS * 40 + q * 8;
  int ao = (mq * 32 + lm) * 40 + half * 8;
  int bo = (nq * 32 + lm) * 40 + half * 8;

  f32x16 acc;
#pragma unroll
  for (int r = 0; r < 16; ++r) acc[r] = 0.f;

#define FA_LOAD(da, db, kb)                                              \
  da = *(const uint4*)(Ag + (size_t)rowS * 1536 + (kb) * 32 + q * 8);    \
  db = *(const uint4*)(Bg + (size_t)rowS * 1536 + (kb) * 32 + q * 8);
#define F_WRITE(buf, sa, sb)                                             \
  *(uint4*)&Al[buf][wr] = sa;                                            \
  *(uint4*)&Bl[buf][wr] = sb;
#define F_COMPUTE(buf)                                                   \
  {                                                                      \
    const unsigned short* Ab = Al[buf];                                  \
    const unsigned short* Bb = Bl[buf];                                  \
    _Pragma("unroll") for (int kk2 = 0; kk2 < 2; ++kk2) {                \
      short8 a8 = *(const short8*)&Ab[ao + kk2 * 16];                    \
      short8 b8 = *(const short8*)&Bb[bo + kk2 * 16];                    \
      acc = __builtin_amdgcn_mfma_f32_32x32x16_bf16(a8, b8, acc, 0, 0, 0); \
    }                                                                    \
  }

  uint4 eA, eB, oA, oB;
  FA_LOAD(eA, eB, 0)
  FA_LOAD(oA, oB, 1)
  F_WRITE(0, eA, eB)
  barrier_lgkm();

  const int NK = 48;
  for (int kb = 0; kb < NK; kb += 2) {
    if (kb + 2 < NK) { FA_LOAD(eA, eB, kb + 2) }
    F_COMPUTE(0)
    if (kb + 1 < NK) { F_WRITE(1, oA, oB) }
    barrier_lgkm();
    if (kb + 1 < NK) {
      if (kb + 3 < NK) { FA_LOAD(oA, oB, kb + 3) }
      F_COMPUTE(1)
      if (kb + 2 < NK) { F_WRITE(0, eA, eB) }
      barrier_lgkm();
    }
  }

  int c = nt * 64 + nq * 32 + lm;
  if (c < D2R) {
    unsigned short* Yk = Ya + (size_t)k * 614400;
    int mb = mt * 64 + mq * 32 + 4 * half;
#pragma unroll
    for (int reg = 0; reg < 16; ++reg) {
      int m = mb + (reg & 3) + 8 * (reg >> 2);
      Yk[(size_t)m * 800 + 2 * c + ri] = (unsigned short)f2bf(acc[reg]);
    }
  }
}

// ---------------- fftBW: fused fftB + wprep ------------------------------
// All 4 kernels k share the B operand (T): grid (12,12), 4 accumulators.
// After the K-loop the block holds SW_k[64x64] for all k in registers ->
// att-combine + f2bf + wBF store in the epilogue. Deletes wprep launch,
// the 9.4MB SW write + 9.4MB read round trip, and 3/4 of B traffic.
__global__ __launch_bounds__(256) void fftBW_kernel(
    const unsigned short* __restrict__ Ya, const unsigned short* __restrict__ T,
    const float* __restrict__ ka, unsigned short* __restrict__ wBF) {
  __shared__ __align__(16) unsigned short Al[2][4][64 * 40], Bl[2][64 * 40];
  int t = threadIdx.x;
  int mt = blockIdx.x, nt = blockIdx.y;
  const unsigned short* Bg = T + (size_t)(nt * 64) * 800;
  int rowS = t >> 2, q = t & 3;
  int lane = t & 63, w = t >> 6;
  int mq = w & 1, nq = w >> 1;
  int lm = lane & 31, half = lane >> 5;
  int wr = rowS * 40 + q * 8;
  int ao = (mq * 32 + lm) * 40 + half * 8;
  int bo = (nq * 32 + lm) * 40 + half * 8;
  size_t arow = (size_t)(mt * 64 + rowS) * 800 + q * 8;  // + k*614400 + kb*32

  f32x16 acc[4];
#pragma unroll
  for (int k = 0; k < 4; ++k)
#pragma unroll
    for (int r = 0; r < 16; ++r) acc[k][r] = 0.f;

  uint4 eA[4], oA[4], eB, oB;
#define BW_LOAD(dA, dB, kb)                                                \
  _Pragma("unroll") for (int k = 0; k < 4; ++k) dA[k] =                    \
      *(const uint4*)(Ya + (size_t)k * 614400 + arow + (kb) * 32);         \
  dB = *(const uint4*)(Bg + (size_t)rowS * 800 + (kb) * 32 + q * 8);
#define BW_WRITE(buf, sA, sB)                                              \
  _Pragma("unroll") for (int k = 0; k < 4; ++k) *(uint4*)&Al[buf][k][wr] = \
      sA[k];                                                               \
  *(uint4*)&Bl[buf][wr] = sB;
#define BW_COMPUTE(buf)                                                    \
  _Pragma("unroll") for (int kk2 = 0; kk2 < 2; ++kk2) {                    \
    short8 b8 = *(const short8*)&Bl[buf][bo + kk2 * 16];                   \
    _Pragma("unroll") for (int k = 0; k < 4; ++k) {                        \
      short8 a8 = *(const short8*)&Al[buf][k][ao + kk2 * 16];              \
      acc[k] =                                                             \
          __builtin_amdgcn_mfma_f32_32x32x16_bf16(a8, b8, acc[k], 0, 0, 0); \
    }                                                                      \
  }

  BW_LOAD(eA, eB, 0)
  BW_LOAD(oA, oB, 1)
  BW_WRITE(0, eA, eB)
  barrier_lgkm();

  const int NK = 25;
  for (int kb = 0; kb < NK; kb += 2) {
    if (kb + 2 < NK) { BW_LOAD(eA, eB, kb + 2) }
    BW_COMPUTE(0)
    if (kb + 1 < NK) { BW_WRITE(1, oA, oB) }
    barrier_lgkm();
    if (kb + 1 < NK) {
      if (kb + 3 < NK) { BW_LOAD(oA, oB, kb + 3) }
      BW_COMPUTE(1)
      if (kb + 2 < NK) { BW_WRITE(0, eA, eB) }
      barrier_lgkm();
    }
  }

  // epilogue: att-weighted combine across k -> bf16 wBF (old wprep math)
  float att[8][4];
#pragma unroll
  for (int b = 0; b < 8; ++b)
#pragma unroll
    for (int k = 0; k < 4; ++k)
      att[b][k] = 0.5f / (1.f + expf(-ka[b * 4 + k]));
  int n = nt * 64 + nq * 32 + lm;  // SW col = ic*3+dx
  int ic = n / 3, dx = n - ic * 3;
  int icb = ic >> 4, ii = ic & 15;
  int mb = mt * 64 + mq * 32 + 4 * half;
#pragma unroll
  for (int reg = 0; reg < 16; ++reg) {
    int m = mb + (reg & 3) + 8 * (reg >> 2);  // SW row = oc*3+dy
    int oc = m / 3, dy = m - oc * 3;
    int s = dy * 3 + dx;
    size_t base = (((size_t)(icb * 9 + s)) * 256 + oc) * 16 + ii;
    float a0 = acc[0][reg], a1 = acc[1][reg], a2 = acc[2][reg],
          a3 = acc[3][reg];
#pragma unroll
    for (int b = 0; b < 8; ++b) {
      float v = att[b][0] * a0 + att[b][1] * a1 + att[b][2] * a2 +
                att[b][3] * a3;
      wBF[base + (size_t)b * 589824] = (unsigned short)f2bf(v);
    }
  }
}

// ---------------- conv v9 (best known: granule LDS + A-reg ring) ---------
__global__ __launch_bounds__(256, 2) void conv_mfma_kernel(
    const float* __restrict__ x, const unsigned short* __restrict__ wBF,
    float* __restrict__ out) {
  __shared__ __align__(16) unsigned char ldsX[2][4 * 2 * 66 * 16];
  int t = threadIdx.x;
  int orig = blockIdx.x;  // grid 512
  int xcd = orig & 7, seq = orig >> 3;
  int slice = xcd * 2 + (seq >> 5);  // = b*2 + oct; XCD x owns b = x
  int pxt = seq & 31;
  int b = slice >> 1, oct = slice & 1;
  int py0 = pxt * 2, oc0 = oct * 128;
  int lane = t & 63, w = t >> 6;
  int ocq = w >> 1, pxq = w & 1;
  int n = lane & 31, half = lane >> 5;

  if (t < 128) {
    int buf = t >> 6, rem = t & 63;
    int idx = rem >> 2, word = rem & 3;
    int r = idx >> 2, icg = (idx >> 1) & 1, c = (idx & 1) ? 65 : 0;
    *(unsigned int*)(&ldsX[buf][(((r * 2 + icg) * 66) + c) * 16 + word * 4]) =
        0u;
  }

  f32x16 acc[2][2];
#pragma unroll
  for (int i = 0; i < 2; ++i)
#pragma unroll
    for (int j = 0; j < 2; ++j)
#pragma unroll
      for (int r = 0; r < 16; ++r) acc[i][j][r] = 0.f;

  int px4 = lane & 15, sub = lane >> 4;
  int iy = py0 - 1 + sub;
  bool valid = (iy >= 0 && iy < 64);
  const float* xpb =
      x + (((size_t)(b * NC + w * 4)) * 64 + (valid ? iy : 0)) * 64 + px4;
  int xwbase = (((sub * 2 + (w >> 1)) * 66) + 1 + px4) * 16 + (w & 1) * 8;
  unsigned char* xw0 = (unsigned char*)&ldsX[0][0] + xwbase;
  unsigned char* xw1 = (unsigned char*)&ldsX[1][0] + xwbase;

  float a[4][4];
#pragma unroll
  for (int j = 0; j < 4; ++j)
#pragma unroll
    for (int pp = 0; pp < 4; ++pp) a[j][pp] = 0.f;
  if (valid) {
#pragma unroll
    for (int j = 0; j < 4; ++j) {
      const float* pj = xpb + (size_t)j * 4096;
#pragma unroll
      for (int pp = 0; pp < 4; ++pp) a[j][pp] = pj[pp * 16];
    }
  }

  const uint4* wg4 = (const uint4*)wBF;
  size_t abase =
      (size_t)b * 144 * 512 + (size_t)(oc0 + ocq * 64 + n) * 2 + half;
  U4S8 pf[9][2];
#pragma unroll
  for (int i = 0; i < 9; ++i) {
    pf[i][0].u4 = wg4[abase + (size_t)i * 512];
    pf[i][1].u4 = wg4[abase + (size_t)i * 512 + 64];
  }

#pragma unroll
  for (int pp = 0; pp < 4; ++pp) {
    uint2 wv;
    wv.x = f2bf(a[0][pp]) | (f2bf(a[1][pp]) << 16);
    wv.y = f2bf(a[2][pp]) | (f2bf(a[3][pp]) << 16);
    *(uint2*)(xw0 + pp * 256) = wv;
  }
  barrier_lgkm();

  for (int icb = 0; icb < 16; ++icb) {
#pragma unroll
    for (int j = 0; j < 4; ++j)
#pragma unroll
      for (int pp = 0; pp < 4; ++pp) a[j][pp] = 0.f;
    if (icb < 15 && valid) {
      const float* p0 = xpb + (size_t)(icb + 1) * 16 * 4096;
#pragma unroll
      for (int j = 0; j < 4; ++j) {
        const float* pj = p0 + (size_t)j * 4096;
#pragma unroll
        for (int pp = 0; pp < 4; ++pp) a[j][pp] = pj[pp * 16];
      }
    }
    const unsigned char* bufR = &ldsX[icb & 1][0];
#pragma unroll
    for (int s = 0; s < 9; ++s) {
      int step = icb * 9 + s;
      int dy = s / 3, dx = s - dy * 3;
      const unsigned char* bb =
          bufR + ((((pxq + dy) * 2 + half) * 66) + n + dx) * 16;
      short8 B0 = *(const short8*)bb;
      short8 B1 = *(const short8*)(bb + 512);
      acc[0][0] = __builtin_amdgcn_mfma_f32_32x32x16_bf16(pf[s][0].s8, B0,
                                                          acc[0][0], 0, 0, 0);
      acc[0][1] = __builtin_amdgcn_mfma_f32_32x32x16_bf16(pf[s][0].s8, B1,
                                                          acc[0][1], 0, 0, 0);
      acc[1][0] = __builtin_amdgcn_mfma_f32_32x32x16_bf16(pf[s][1].s8, B0,
                                                          acc[1][0], 0, 0, 0);
      acc[1][1] = __builtin_amdgcn_mfma_f32_32x32x16_bf16(pf[s][1].s8, B1,
                                                          acc[1][1], 0, 0, 0);
      if (icb < 15) {
        pf[s][0].u4 = wg4[abase + (size_t)(step + 9) * 512];
        pf[s][1].u4 = wg4[abase + (size_t)(step + 9) * 512 + 64];
      }
    }
    if (icb < 15) {
      unsigned char* xw = (icb & 1) ? xw0 : xw1;
#pragma unroll
      for (int pp = 0; pp < 4; ++pp) {
        uint2 wv;
        wv.x = f2bf(a[0][pp]) | (f2bf(a[1][pp]) << 16);
        wv.y = f2bf(a[2][pp]) | (f2bf(a[3][pp]) << 16);
        *(uint2*)(xw + pp * 256) = wv;
      }
    }
    barrier_lgkm();
  }

  int py = py0 + pxq;
#pragma unroll
  for (int osub = 0; osub < 2; ++osub)
#pragma unroll
    for (int psub = 0; psub < 2; ++psub) {
      int OC = oc0 + ocq * 64 + osub * 32 + 4 * half;
      int pxc = psub * 32 + n;
      float* op = out + (((size_t)(b * NC + OC)) * 64 + py) * 64 + pxc;
#pragma unroll
      for (int reg = 0; reg < 16; ++reg) {
        int ocm = (reg & 3) + 8 * (reg >> 2);
        op[(size_t)ocm * 4096] = acc[osub][psub][reg];
      }
    }
}

extern "C" void kernel_launch(void* const* d_in, const int* in_sizes, int n_in,
                              void* d_out, int out_size, void* d_ws,
                              size_t ws_size, hipStream_t stream) {
  const float* x = (const float*)d_in[0];
  const float* dw = (const float*)d_in[1];
  const float* ka = (const float*)d_in[2];
  const int* fh = (const int*)d_in[3];
  const int* fw = (const int*)d_in[4];
  float* out = (float*)d_out;
  unsigned int* ws = (unsigned int*)d_ws;
  const unsigned short* specB = (const unsigned short*)d_ws;
  const unsigned short* Atw = (const unsigned short*)((char*)d_ws + 6291456);
  unsigned short* Ya = (unsigned short*)((char*)d_ws + 11010048);
  const unsigned short* T = (const unsigned short*)((char*)d_ws + 15925248);
  unsigned short* wBF = (unsigned short*)d_ws;  // overlays specB+Atw (dead)

  hipLaunchKernelGGL(prep_kernel, dim3(2841), dim3(256), 0, stream, dw, fh,
                     fw, ws);
  hipLaunchKernelGGL(fftA_kernel, dim3(12, 7, 8), dim3(256), 0, stream, Atw,
                     specB, Ya);
  hipLaunchKernelGGL(fftBW_kernel, dim3(12, 12), dim3(256), 0, stream, Ya, T,
                     ka, wBF);
  hipLaunchKernelGGL(conv_mfma_kernel, dim3(512), dim3(256), 0, stream, x,
                     wBF, out);
}